// Round 19
// baseline (271.434 us; speedup 1.0000x reference)
//
#include <hip/hip_runtime.h>
#include <stdint.h>

// ---------------------------------------------------------------------------
// D-ETM decoder: alphas = mu + eps*exp(0.5*ls); KL; beta = softmax(alphas@W^T)
// out = [beta (125M f32), kl (1 f32)]
//
// R19: R18 (best, 261.2us) + swapped-operand pass2.
//   Both passes now compute the transposed tile (COMPUTE(Ws,As)), so the
//   vocab index is lane-contiguous (i = lhi*4+0..3): pass2's epilogue
//   becomes 32 float4 stores/thread instead of 128 dword stores. Same
//   products, same k-order => logits bitwise identical; absmax must remain
//   exactly 0.8764648. pass1, k1, k3, host byte-identical to R18.
//
// ws (~18 MB): Wp8[50176][256] u8 @0; Ap8[2560][256] u8 @12,845,056;
//   pm[196][2560] f32 @13,500,416; ps @15,507,456; bs @17,514,496;
//   Ms @17,524,736; Ss @17,534,976
// ---------------------------------------------------------------------------

typedef float f32x4 __attribute__((ext_vector_type(4)));
typedef int i32x8 __attribute__((ext_vector_type(8)));

#define TT 50
#define KTOP 50
#define RHO 256
#define VOCAB 50000
#define NROWS 2500
#define MPAD 2560
#define BM 256
#define BN 256
#define BK 128
#define NTN 196          // ceil(50000/256)
#define NTM 10           // 2560/256
#define NPADV (NTN * BN) // 50176
#define NVB_W 12544      // NPADV*256/1024 chunks of W per 256-thr block
#define LOG_DELTA (-5.29831736f)

#define AS1(p) ((__attribute__((address_space(1))) void*)(uintptr_t)(p))
#define AS3(p) ((__attribute__((address_space(3))) void*)(p))

__device__ __forceinline__ uint8_t to_fp8(float x) {
    int pk = __builtin_amdgcn_cvt_pk_fp8_f32(x, 0.0f, 0, false);
    return (uint8_t)(pk & 0xFF);
}

// ---- K1: grid-stride: A rows + KL (vb<MPAD); W cast float4 (vb>=MPAD) -----
__global__ __launch_bounds__(256) void k1_prep(
    const float* __restrict__ mu, const float* __restrict__ ls,
    const float* __restrict__ eps, const float* __restrict__ W,
    uint8_t* __restrict__ Ap8, uint8_t* __restrict__ Wp8,
    float* __restrict__ blksum)
{
    __shared__ float sred[256];
    const int r = threadIdx.x;
    for (int vb = blockIdx.x; vb < MPAD + NVB_W; vb += gridDim.x) {
        if (vb >= MPAD) {
            long e0 = (long)(vb - MPAD) * 1024 + r * 4;
            long v = e0 >> 8;
            uchar4 o;
            if (v < VOCAB) {
                float4 w = *(const float4*)(W + e0);
                o.x = to_fp8(w.x); o.y = to_fp8(w.y);
                o.z = to_fp8(w.z); o.w = to_fp8(w.w);
            } else {
                o.x = o.y = o.z = o.w = 0;
            }
            *(uchar4*)(Wp8 + e0) = o;
            continue;
        }
        int b = vb;
        if (b >= NROWS) { Ap8[(long)b * RHO + r] = 0; continue; }
        int t = b / KTOP;
        int k = b - t * KTOP;
        long iMu = ((long)k * TT + t) * RHO + r;
        long iEp = ((long)t * KTOP + k) * RHO + r;
        float m = mu[iMu], l = ls[iMu], e = eps[iEp];
        float alpha = fmaf(e, __expf(0.5f * l), m);
        Ap8[(long)b * RHO + r] = to_fp8(alpha);

        float p_mu = 0.0f, p_ls = 0.0f, denom = 1.0f + 1e-6f;
        if (t > 0) {
            float m0 = mu[iMu - RHO];
            float l0 = ls[iMu - RHO];
            float e0 = eps[iEp - (long)KTOP * RHO];
            p_mu = fmaf(e0, __expf(0.5f * l0), m0);
            p_ls = LOG_DELTA;
            denom = 0.005f + 1e-6f;
        }
        float sq = __expf(l);
        float d = m - p_mu;
        float term = (sq + d * d) / denom - 1.0f + p_ls - l;

        sred[r] = term;
        __syncthreads();
        for (int s = 128; s > 0; s >>= 1) {
            if (r < s) sred[r] += sred[r + s];
            __syncthreads();
        }
        if (r == 0) blksum[b] = sred[0];
        __syncthreads();
    }
}

// ---- shared fp8 GEMM machinery --------------------------------------------
// LDS rows are 128 B. Stage places global 16B chunk (c ^ (row&7)) at
// physical chunk c; ds_read of logical 8B unit u uses physical u^((row&7)<<1).
#define GEMM_PRELUDE(EXTRA)                                                    \
    __shared__ alignas(16) char lds_raw[131072 + EXTRA];                       \
    uint8_t* As0 = (uint8_t*)lds_raw;                /* [256][128] 32 KB */    \
    uint8_t* Ws0 = (uint8_t*)(lds_raw + 32768);                                \
    uint8_t* As1 = (uint8_t*)(lds_raw + 65536);                                \
    uint8_t* Ws1 = (uint8_t*)(lds_raw + 98304);                                \
    const int tid = threadIdx.x;                                               \
    const int wave = tid >> 6;                                                 \
    const int lane = tid & 63;                                                 \
    const int bid = blockIdx.x;                                                \
    const int orig = (bid & 7) * 245 + (bid >> 3);   /* 1960 = 8*245 */        \
    const int tm = orig % NTM;                                                 \
    const int tn = orig / NTM;                                                 \
    const int wr = wave >> 2;    /* 0..1 */                                    \
    const int wc = wave & 3;     /* 0..3 */                                    \
    const int lhi = lane >> 4;                                                 \
    const int llo = lane & 15;                                                 \
    f32x4 acc[8][4];                                                           \
    _Pragma("unroll")                                                          \
    for (int m = 0; m < 8; ++m)                                                \
        _Pragma("unroll")                                                      \
        for (int n = 0; n < 4; ++n)                                            \
            _Pragma("unroll")                                                  \
            for (int i = 0; i < 4; ++i) acc[m][n][i] = 0.0f;                   \
    const long arow0 = (long)tm * BM;                                          \
    const long wrow0 = (long)tn * BN;

#define STAGE(AB, WB, kt)                                                      \
    {                                                                          \
        _Pragma("unroll")                                                      \
        for (int j = 0; j < 4; ++j) {                                          \
            int row = j * 64 + (tid >> 3);           /* 0..255 */              \
            int c   = tid & 7;                       /* 16B chunk */           \
            int gc  = (c ^ (row & 7)) * 16;                                    \
            const uint8_t* sA = Ap8 + (arow0 + row) * RHO + (kt) * BK + gc;    \
            __builtin_amdgcn_global_load_lds(AS1(sA),                          \
                AS3(AB + row * BK + c * 16), 16, 0, 0);                        \
            const uint8_t* sW = Wp8 + (wrow0 + row) * RHO + (kt) * BK + gc;    \
            __builtin_amdgcn_global_load_lds(AS1(sW),                          \
                AS3(WB + row * BK + c * 16), 16, 0, 0);                        \
        }                                                                      \
    }

// Fragment: lane covers k = lhi*32..+31 = logical 8B units lhi*4+p, p=0..3
#define LOADFRAG(dst, BASE, r)                                                 \
    {                                                                          \
        union { long l[4]; i32x8 v; } u_;                                      \
        _Pragma("unroll")                                                      \
        for (int p = 0; p < 4; ++p) {                                          \
            int unit = (lhi * 4 + p) ^ (((r) & 7) << 1);                       \
            u_.l[p] = *(const long*)&BASE[(r) * BK + (unit << 3)];             \
        }                                                                      \
        dst = u_.v;                                                            \
    }

// swapped: acc[m][n][i] = logit[row wc*64+n*16+llo]
//                              [vocab tn*256 + wr*128 + m*16 + lhi*4 + i]
#define COMPUTE(AB, WB)                                                        \
    {                                                                          \
        i32x8 bfr[4];                                                          \
        _Pragma("unroll")                                                      \
        for (int n = 0; n < 4; ++n) {                                          \
            int r = wc * 64 + n * 16 + llo;                                    \
            LOADFRAG(bfr[n], WB, r)                                            \
        }                                                                      \
        _Pragma("unroll")                                                      \
        for (int h = 0; h < 2; ++h) {                                          \
            i32x8 af[4];                                                       \
            _Pragma("unroll")                                                  \
            for (int mm = 0; mm < 4; ++mm) {                                   \
                int r = wr * 128 + (h * 4 + mm) * 16 + llo;                    \
                LOADFRAG(af[mm], AB, r)                                        \
            }                                                                  \
            _Pragma("unroll")                                                  \
            for (int mm = 0; mm < 4; ++mm)                                     \
                _Pragma("unroll")                                              \
                for (int n = 0; n < 4; ++n)                                    \
                    acc[h * 4 + mm][n] =                                       \
                        __builtin_amdgcn_mfma_scale_f32_16x16x128_f8f6f4(      \
                            af[mm], bfr[n], acc[h * 4 + mm][n],                \
                            0, 0, 0, 0x7F7F7F7F, 0, 0x7F7F7F7F);               \
        }                                                                      \
    }

// ---- K2 pass 1: swapped-operand GEMM -> per-tile (max, sumexp) ------------
__global__ __launch_bounds__(512, 2) void k2_pass1(
    const uint8_t* __restrict__ Ap8, const uint8_t* __restrict__ Wp8,
    float* __restrict__ pm, float* __restrict__ ps)
{
    GEMM_PRELUDE(4096)
    float* red_m = (float*)(lds_raw + 131072);       // [2][256]
    float* red_s = (float*)(lds_raw + 133120);       // [2][256]

    STAGE(As0, Ws0, 0)
    STAGE(As1, Ws1, 1)
    asm volatile("s_waitcnt vmcnt(8)\n\ts_barrier" ::: "memory");
    __builtin_amdgcn_sched_barrier(0);
    COMPUTE(Ws0, As0)
    asm volatile("s_waitcnt vmcnt(0)\n\ts_barrier" ::: "memory");
    __builtin_amdgcn_sched_barrier(0);
    COMPUTE(Ws1, As1)

    // per-row reduce: local over (m,i), cross-lane over lhi (xor 16, 32)
#pragma unroll
    for (int n = 0; n < 4; ++n) {
        float mx = -1e30f;
#pragma unroll
        for (int m = 0; m < 8; ++m)
#pragma unroll
            for (int i = 0; i < 4; ++i) {
                int cg = tn * BN + wr * 128 + m * 16 + lhi * 4 + i;
                if (cg < VOCAB) mx = fmaxf(mx, acc[m][n][i]);
            }
        mx = fmaxf(mx, __shfl_xor(mx, 16));
        mx = fmaxf(mx, __shfl_xor(mx, 32));
        float sm = 0.0f;
#pragma unroll
        for (int m = 0; m < 8; ++m)
#pragma unroll
            for (int i = 0; i < 4; ++i) {
                int cg = tn * BN + wr * 128 + m * 16 + lhi * 4 + i;
                if (cg < VOCAB) sm += __expf(acc[m][n][i] - mx);
            }
        sm += __shfl_xor(sm, 16);
        sm += __shfl_xor(sm, 32);
        if (lhi == 0) {
            int rl = wc * 64 + n * 16 + llo;     // 0..255 (A-row in tile)
            red_m[wr * 256 + rl] = mx;
            red_s[wr * 256 + rl] = sm;
        }
    }
    __syncthreads();
    if (tid < BM) {
        float m0 = red_m[tid], m1 = red_m[256 + tid];
        float M = fmaxf(m0, m1);
        float S = red_s[tid] * __expf(m0 - M) + red_s[256 + tid] * __expf(m1 - M);
        long idx = (long)tn * MPAD + tm * BM + tid;
        pm[idx] = M;
        ps[idx] = S;
    }
}

// ---- K3: coalesced per-row (M, S); block 40 = kl reduce -------------------
__global__ __launch_bounds__(256) void k3_stats(
    const float* __restrict__ pm, const float* __restrict__ ps,
    const float* __restrict__ blksum,
    float* __restrict__ Ms, float* __restrict__ Ss, float* __restrict__ kl_out)
{
    if (blockIdx.x == 40) {
        __shared__ float sred[256];
        float s = 0.0f;
        for (int i = threadIdx.x; i < NROWS; i += 256) s += blksum[i];
        sred[threadIdx.x] = s;
        __syncthreads();
        for (int st = 128; st > 0; st >>= 1) {
            if (threadIdx.x < st) sred[threadIdx.x] += sred[threadIdx.x + st];
            __syncthreads();
        }
        if (threadIdx.x == 0) kl_out[0] = 0.5f * sred[0];
        return;
    }
    const int r = threadIdx.x & 63;      // row within 64-row group
    const int jg = threadIdx.x >> 6;     // 0..3
    const int row = blockIdx.x * 64 + r; // < 2560
    float m_loc = -1e30f, s_loc = 0.0f;
    for (int j = jg; j < NTN; j += 4) {  // wave reads 64 consecutive rows
        float mj = pm[(long)j * MPAD + row];
        float sj = ps[(long)j * MPAD + row];
        if (mj > m_loc) { s_loc = s_loc * __expf(m_loc - mj) + sj; m_loc = mj; }
        else            { s_loc += sj * __expf(mj - m_loc); }
    }
    __shared__ float sm[4][64];
    __shared__ float ss[4][64];
    sm[jg][r] = m_loc; ss[jg][r] = s_loc;
    __syncthreads();
    if (threadIdx.x < 64) {
        float M = sm[0][r];
#pragma unroll
        for (int w = 1; w < 4; ++w) M = fmaxf(M, sm[w][r]);
        float S = 0.0f;
#pragma unroll
        for (int w = 0; w < 4; ++w) S += ss[w][r] * __expf(sm[w][r] - M);
        int rw = blockIdx.x * 64 + r;
        if (rw < NROWS) { Ms[rw] = M; Ss[rw] = S; }
    }
}

// ---- K2 pass 2: swapped GEMM -> beta via float4 stores -> d_out -----------
// acc[m][n][i] = logit[row wc*64+n*16+llo][vocab tn*256+wr*128+m*16+lhi*4+i]
// i is vocab-contiguous => one float4 store per (m,n).
__global__ __launch_bounds__(512, 2) void k2_pass2(
    const uint8_t* __restrict__ Ap8, const uint8_t* __restrict__ Wp8,
    const float* __restrict__ Ms, const float* __restrict__ Ss,
    float* __restrict__ out)
{
    GEMM_PRELUDE(2048)
    float* ms_lds = (float*)(lds_raw + 131072);      // [256]
    float* ss_lds = (float*)(lds_raw + 132096);      // [256] (1/S)

    STAGE(As0, Ws0, 0)
    STAGE(As1, Ws1, 1)
    asm volatile("s_waitcnt vmcnt(8)\n\ts_barrier" ::: "memory");
    __builtin_amdgcn_sched_barrier(0);
    COMPUTE(Ws0, As0)
    asm volatile("s_waitcnt vmcnt(0)\n\ts_barrier" ::: "memory");
    __builtin_amdgcn_sched_barrier(0);
    COMPUTE(Ws1, As1)

    // load row stats AFTER the K-loop (keeps the vmcnt counts exact)
    if (tid < BM) {
        long rg = arow0 + tid;
        float Mv = 0.0f, Sv = 1.0f;
        if (rg < NROWS) { Mv = Ms[rg]; Sv = Ss[rg]; }
        ms_lds[tid] = Mv;
        ss_lds[tid] = 1.0f / Sv;
    }
    __syncthreads();

#pragma unroll
    for (int n = 0; n < 4; ++n) {
        int rl = wc * 64 + n * 16 + llo;             // tile row
        long rg = arow0 + rl;
        if (rg < NROWS) {
            float M = ms_lds[rl];
            float iS = ss_lds[rl];
            float* orow = out + rg * (long)VOCAB;
#pragma unroll
            for (int m = 0; m < 8; ++m) {
                int cg = tn * BN + wr * 128 + m * 16 + lhi * 4;
                if (cg < VOCAB) {                    // 4 | VOCAB => all-or-none
                    float4 v;
                    v.x = __expf(acc[m][n][0] - M) * iS;
                    v.y = __expf(acc[m][n][1] - M) * iS;
                    v.z = __expf(acc[m][n][2] - M) * iS;
                    v.w = __expf(acc[m][n][3] - M) * iS;
                    *(float4*)(orow + cg) = v;
                }
            }
        }
    }
}

extern "C" void kernel_launch(void* const* d_in, const int* in_sizes, int n_in,
                              void* d_out, int out_size, void* d_ws, size_t ws_size,
                              hipStream_t stream) {
    const float* mu  = (const float*)d_in[0];
    const float* ls  = (const float*)d_in[1];
    const float* eps = (const float*)d_in[2];
    const float* W   = (const float*)d_in[3];
    char* ws = (char*)d_ws;

    uint8_t* Wp8 = (uint8_t*)(ws);
    uint8_t* Ap8 = (uint8_t*)(ws + 12845056L);
    float* pm  = (float*)(ws + 13500416L);
    float* ps  = (float*)(ws + 15507456L);
    float* bs  = (float*)(ws + 17514496L);
    float* Ms  = (float*)(ws + 17524736L);
    float* Ss  = (float*)(ws + 17534976L);
    float* kl  = (float*)d_out + 125000000L;

    k1_prep<<<2048, 256, 0, stream>>>(mu, ls, eps, W, Ap8, Wp8, bs);
    k2_pass1<<<NTM * NTN, 512, 0, stream>>>(Ap8, Wp8, pm, ps);
    k3_stats<<<41, 256, 0, stream>>>(pm, ps, bs, Ms, Ss, kl);
    k2_pass2<<<NTM * NTN, 512, 0, stream>>>(Ap8, Wp8, Ms, Ss, (float*)d_out);
}

// Round 20
// 259.633 us; speedup vs baseline: 1.0455x; 1.0455x over previous
//
#include <hip/hip_runtime.h>
#include <stdint.h>

// ---------------------------------------------------------------------------
// D-ETM decoder: alphas = mu + eps*exp(0.5*ls); KL; beta = softmax(alphas@W^T)
// out = [beta (125M f32), kl (1 f32)]
//
// R20: R18 (best, 261.2us) + pass2 early row-stat prefetch.
//   R19's float4-store pass2 regressed (+10us: 16-row scatter per instr vs
//   R18's 4-row/64B-sector pattern) — reverted. Only change vs R18: pass2
//   issues its Ms/Ss loads BEFORE the STAGEs, so the same vmcnt(8) gate
//   covers stats+tile0 and the stat latency hides under the K-loop.
//   Logits bitwise identical; absmax must remain exactly 0.8764648.
//
// ws (~18 MB): Wp8[50176][256] u8 @0; Ap8[2560][256] u8 @12,845,056;
//   pm[196][2560] f32 @13,500,416; ps @15,507,456; bs @17,514,496;
//   Ms @17,524,736; Ss @17,534,976
// ---------------------------------------------------------------------------

typedef float f32x4 __attribute__((ext_vector_type(4)));
typedef int i32x8 __attribute__((ext_vector_type(8)));

#define TT 50
#define KTOP 50
#define RHO 256
#define VOCAB 50000
#define NROWS 2500
#define MPAD 2560
#define BM 256
#define BN 256
#define BK 128
#define NTN 196          // ceil(50000/256)
#define NTM 10           // 2560/256
#define NPADV (NTN * BN) // 50176
#define NVB_W 12544      // NPADV*256/1024 chunks of W per 256-thr block
#define LOG_DELTA (-5.29831736f)

#define AS1(p) ((__attribute__((address_space(1))) void*)(uintptr_t)(p))
#define AS3(p) ((__attribute__((address_space(3))) void*)(p))

__device__ __forceinline__ uint8_t to_fp8(float x) {
    int pk = __builtin_amdgcn_cvt_pk_fp8_f32(x, 0.0f, 0, false);
    return (uint8_t)(pk & 0xFF);
}

// ---- K1: grid-stride: A rows + KL (vb<MPAD); W cast float4 (vb>=MPAD) -----
__global__ __launch_bounds__(256) void k1_prep(
    const float* __restrict__ mu, const float* __restrict__ ls,
    const float* __restrict__ eps, const float* __restrict__ W,
    uint8_t* __restrict__ Ap8, uint8_t* __restrict__ Wp8,
    float* __restrict__ blksum)
{
    __shared__ float sred[256];
    const int r = threadIdx.x;
    for (int vb = blockIdx.x; vb < MPAD + NVB_W; vb += gridDim.x) {
        if (vb >= MPAD) {
            long e0 = (long)(vb - MPAD) * 1024 + r * 4;
            long v = e0 >> 8;
            uchar4 o;
            if (v < VOCAB) {
                float4 w = *(const float4*)(W + e0);
                o.x = to_fp8(w.x); o.y = to_fp8(w.y);
                o.z = to_fp8(w.z); o.w = to_fp8(w.w);
            } else {
                o.x = o.y = o.z = o.w = 0;
            }
            *(uchar4*)(Wp8 + e0) = o;
            continue;
        }
        int b = vb;
        if (b >= NROWS) { Ap8[(long)b * RHO + r] = 0; continue; }
        int t = b / KTOP;
        int k = b - t * KTOP;
        long iMu = ((long)k * TT + t) * RHO + r;
        long iEp = ((long)t * KTOP + k) * RHO + r;
        float m = mu[iMu], l = ls[iMu], e = eps[iEp];
        float alpha = fmaf(e, __expf(0.5f * l), m);
        Ap8[(long)b * RHO + r] = to_fp8(alpha);

        float p_mu = 0.0f, p_ls = 0.0f, denom = 1.0f + 1e-6f;
        if (t > 0) {
            float m0 = mu[iMu - RHO];
            float l0 = ls[iMu - RHO];
            float e0 = eps[iEp - (long)KTOP * RHO];
            p_mu = fmaf(e0, __expf(0.5f * l0), m0);
            p_ls = LOG_DELTA;
            denom = 0.005f + 1e-6f;
        }
        float sq = __expf(l);
        float d = m - p_mu;
        float term = (sq + d * d) / denom - 1.0f + p_ls - l;

        sred[r] = term;
        __syncthreads();
        for (int s = 128; s > 0; s >>= 1) {
            if (r < s) sred[r] += sred[r + s];
            __syncthreads();
        }
        if (r == 0) blksum[b] = sred[0];
        __syncthreads();
    }
}

// ---- shared fp8 GEMM machinery --------------------------------------------
// LDS rows are 128 B. Stage places global 16B chunk (c ^ (row&7)) at
// physical chunk c; ds_read of logical 8B unit u uses physical u^((row&7)<<1).
#define GEMM_PRELUDE(EXTRA)                                                    \
    __shared__ alignas(16) char lds_raw[131072 + EXTRA];                       \
    uint8_t* As0 = (uint8_t*)lds_raw;                /* [256][128] 32 KB */    \
    uint8_t* Ws0 = (uint8_t*)(lds_raw + 32768);                                \
    uint8_t* As1 = (uint8_t*)(lds_raw + 65536);                                \
    uint8_t* Ws1 = (uint8_t*)(lds_raw + 98304);                                \
    const int tid = threadIdx.x;                                               \
    const int wave = tid >> 6;                                                 \
    const int lane = tid & 63;                                                 \
    const int bid = blockIdx.x;                                                \
    const int orig = (bid & 7) * 245 + (bid >> 3);   /* 1960 = 8*245 */        \
    const int tm = orig % NTM;                                                 \
    const int tn = orig / NTM;                                                 \
    const int wr = wave >> 2;    /* 0..1 */                                    \
    const int wc = wave & 3;     /* 0..3 */                                    \
    const int lhi = lane >> 4;                                                 \
    const int llo = lane & 15;                                                 \
    f32x4 acc[8][4];                                                           \
    _Pragma("unroll")                                                          \
    for (int m = 0; m < 8; ++m)                                                \
        _Pragma("unroll")                                                      \
        for (int n = 0; n < 4; ++n)                                            \
            _Pragma("unroll")                                                  \
            for (int i = 0; i < 4; ++i) acc[m][n][i] = 0.0f;                   \
    const long arow0 = (long)tm * BM;                                          \
    const long wrow0 = (long)tn * BN;

#define STAGE(AB, WB, kt)                                                      \
    {                                                                          \
        _Pragma("unroll")                                                      \
        for (int j = 0; j < 4; ++j) {                                          \
            int row = j * 64 + (tid >> 3);           /* 0..255 */              \
            int c   = tid & 7;                       /* 16B chunk */           \
            int gc  = (c ^ (row & 7)) * 16;                                    \
            const uint8_t* sA = Ap8 + (arow0 + row) * RHO + (kt) * BK + gc;    \
            __builtin_amdgcn_global_load_lds(AS1(sA),                          \
                AS3(AB + row * BK + c * 16), 16, 0, 0);                        \
            const uint8_t* sW = Wp8 + (wrow0 + row) * RHO + (kt) * BK + gc;    \
            __builtin_amdgcn_global_load_lds(AS1(sW),                          \
                AS3(WB + row * BK + c * 16), 16, 0, 0);                        \
        }                                                                      \
    }

// Fragment: lane covers k = lhi*32..+31 = logical 8B units lhi*4+p, p=0..3
#define LOADFRAG(dst, BASE, r)                                                 \
    {                                                                          \
        union { long l[4]; i32x8 v; } u_;                                      \
        _Pragma("unroll")                                                      \
        for (int p = 0; p < 4; ++p) {                                          \
            int unit = (lhi * 4 + p) ^ (((r) & 7) << 1);                       \
            u_.l[p] = *(const long*)&BASE[(r) * BK + (unit << 3)];             \
        }                                                                      \
        dst = u_.v;                                                            \
    }

#define COMPUTE(AB, WB)                                                        \
    {                                                                          \
        i32x8 bfr[4];                                                          \
        _Pragma("unroll")                                                      \
        for (int n = 0; n < 4; ++n) {                                          \
            int r = wc * 64 + n * 16 + llo;                                    \
            LOADFRAG(bfr[n], WB, r)                                            \
        }                                                                      \
        _Pragma("unroll")                                                      \
        for (int h = 0; h < 2; ++h) {                                          \
            i32x8 af[4];                                                       \
            _Pragma("unroll")                                                  \
            for (int mm = 0; mm < 4; ++mm) {                                   \
                int r = wr * 128 + (h * 4 + mm) * 16 + llo;                    \
                LOADFRAG(af[mm], AB, r)                                        \
            }                                                                  \
            _Pragma("unroll")                                                  \
            for (int mm = 0; mm < 4; ++mm)                                     \
                _Pragma("unroll")                                              \
                for (int n = 0; n < 4; ++n)                                    \
                    acc[h * 4 + mm][n] =                                       \
                        __builtin_amdgcn_mfma_scale_f32_16x16x128_f8f6f4(      \
                            af[mm], bfr[n], acc[h * 4 + mm][n],                \
                            0, 0, 0, 0x7F7F7F7F, 0, 0x7F7F7F7F);               \
        }                                                                      \
    }

// ---- K2 pass 1: swapped-operand GEMM -> per-tile (max, sumexp) ------------
// COMPUTE(Ws,As): acc[m][n][i] = logit[row wc*64+n*16+llo]
//                                      [vocab tn*256 + wr*128 + m*16 + lhi*4+i]
__global__ __launch_bounds__(512, 2) void k2_pass1(
    const uint8_t* __restrict__ Ap8, const uint8_t* __restrict__ Wp8,
    float* __restrict__ pm, float* __restrict__ ps)
{
    GEMM_PRELUDE(4096)
    float* red_m = (float*)(lds_raw + 131072);       // [2][256]
    float* red_s = (float*)(lds_raw + 133120);       // [2][256]

    STAGE(As0, Ws0, 0)
    STAGE(As1, Ws1, 1)
    asm volatile("s_waitcnt vmcnt(8)\n\ts_barrier" ::: "memory");
    __builtin_amdgcn_sched_barrier(0);
    COMPUTE(Ws0, As0)
    asm volatile("s_waitcnt vmcnt(0)\n\ts_barrier" ::: "memory");
    __builtin_amdgcn_sched_barrier(0);
    COMPUTE(Ws1, As1)

    // per-row reduce: local over (m,i), cross-lane over lhi (xor 16, 32)
#pragma unroll
    for (int n = 0; n < 4; ++n) {
        float mx = -1e30f;
#pragma unroll
        for (int m = 0; m < 8; ++m)
#pragma unroll
            for (int i = 0; i < 4; ++i) {
                int cg = tn * BN + wr * 128 + m * 16 + lhi * 4 + i;
                if (cg < VOCAB) mx = fmaxf(mx, acc[m][n][i]);
            }
        mx = fmaxf(mx, __shfl_xor(mx, 16));
        mx = fmaxf(mx, __shfl_xor(mx, 32));
        float sm = 0.0f;
#pragma unroll
        for (int m = 0; m < 8; ++m)
#pragma unroll
            for (int i = 0; i < 4; ++i) {
                int cg = tn * BN + wr * 128 + m * 16 + lhi * 4 + i;
                if (cg < VOCAB) sm += __expf(acc[m][n][i] - mx);
            }
        sm += __shfl_xor(sm, 16);
        sm += __shfl_xor(sm, 32);
        if (lhi == 0) {
            int rl = wc * 64 + n * 16 + llo;     // 0..255 (A-row in tile)
            red_m[wr * 256 + rl] = mx;
            red_s[wr * 256 + rl] = sm;
        }
    }
    __syncthreads();
    if (tid < BM) {
        float m0 = red_m[tid], m1 = red_m[256 + tid];
        float M = fmaxf(m0, m1);
        float S = red_s[tid] * __expf(m0 - M) + red_s[256 + tid] * __expf(m1 - M);
        long idx = (long)tn * MPAD + tm * BM + tid;
        pm[idx] = M;
        ps[idx] = S;
    }
}

// ---- K3: coalesced per-row (M, S); block 40 = kl reduce -------------------
__global__ __launch_bounds__(256) void k3_stats(
    const float* __restrict__ pm, const float* __restrict__ ps,
    const float* __restrict__ blksum,
    float* __restrict__ Ms, float* __restrict__ Ss, float* __restrict__ kl_out)
{
    if (blockIdx.x == 40) {
        __shared__ float sred[256];
        float s = 0.0f;
        for (int i = threadIdx.x; i < NROWS; i += 256) s += blksum[i];
        sred[threadIdx.x] = s;
        __syncthreads();
        for (int st = 128; st > 0; st >>= 1) {
            if (threadIdx.x < st) sred[threadIdx.x] += sred[threadIdx.x + st];
            __syncthreads();
        }
        if (threadIdx.x == 0) kl_out[0] = 0.5f * sred[0];
        return;
    }
    const int r = threadIdx.x & 63;      // row within 64-row group
    const int jg = threadIdx.x >> 6;     // 0..3
    const int row = blockIdx.x * 64 + r; // < 2560
    float m_loc = -1e30f, s_loc = 0.0f;
    for (int j = jg; j < NTN; j += 4) {  // wave reads 64 consecutive rows
        float mj = pm[(long)j * MPAD + row];
        float sj = ps[(long)j * MPAD + row];
        if (mj > m_loc) { s_loc = s_loc * __expf(m_loc - mj) + sj; m_loc = mj; }
        else            { s_loc += sj * __expf(mj - m_loc); }
    }
    __shared__ float sm[4][64];
    __shared__ float ss[4][64];
    sm[jg][r] = m_loc; ss[jg][r] = s_loc;
    __syncthreads();
    if (threadIdx.x < 64) {
        float M = sm[0][r];
#pragma unroll
        for (int w = 1; w < 4; ++w) M = fmaxf(M, sm[w][r]);
        float S = 0.0f;
#pragma unroll
        for (int w = 0; w < 4; ++w) S += ss[w][r] * __expf(sm[w][r] - M);
        int rw = blockIdx.x * 64 + r;
        if (rw < NROWS) { Ms[rw] = M; Ss[rw] = S; }
    }
}

// ---- K2 pass 2: fp8 GEMM -> beta = exp(acc - M)/S -> d_out ----------------
// Row stats prefetched BEFORE the STAGEs: they are the oldest vm-ops, so the
// same vmcnt(8) gate covers stats+tile0 (waves without stat loads just gate
// tile0). Stats written to LDS before COMPUTE(0); epilogue reads after the
// vmcnt(0) barrier.
__global__ __launch_bounds__(512, 2) void k2_pass2(
    const uint8_t* __restrict__ Ap8, const uint8_t* __restrict__ Wp8,
    const float* __restrict__ Ms, const float* __restrict__ Ss,
    float* __restrict__ out)
{
    GEMM_PRELUDE(2048)
    float* ms_lds = (float*)(lds_raw + 131072);      // [256]
    float* ss_lds = (float*)(lds_raw + 132096);      // [256] (1/S)

    float Mv = 0.0f, Sv = 1.0f;
    const bool statlane = (tid < BM) && (arow0 + tid < NROWS);
    if (statlane) {
        Mv = Ms[arow0 + tid];
        Sv = Ss[arow0 + tid];
    }
    STAGE(As0, Ws0, 0)
    STAGE(As1, Ws1, 1)
    asm volatile("s_waitcnt vmcnt(8)\n\ts_barrier" ::: "memory");
    __builtin_amdgcn_sched_barrier(0);
    if (tid < BM) {
        ms_lds[tid] = Mv;
        ss_lds[tid] = 1.0f / Sv;
    }
    COMPUTE(As0, Ws0)
    asm volatile("s_waitcnt vmcnt(0)\n\ts_barrier" ::: "memory");
    __builtin_amdgcn_sched_barrier(0);
    COMPUTE(As1, Ws1)
    __syncthreads();   // ms_lds/ss_lds writes visible to all waves

#pragma unroll
    for (int m = 0; m < 8; ++m) {
#pragma unroll
        for (int i = 0; i < 4; ++i) {
            int rl = wr * 128 + m * 16 + lhi * 4 + i;
            long rg = arow0 + rl;
            if (rg < NROWS) {
                float M = ms_lds[rl];
                float invS = ss_lds[rl];
                float* orow = out + rg * (long)VOCAB;
#pragma unroll
                for (int n = 0; n < 4; ++n) {
                    int cg = tn * BN + wc * 64 + n * 16 + llo;
                    if (cg < VOCAB) orow[cg] = __expf(acc[m][n][i] - M) * invS;
                }
            }
        }
    }
}

extern "C" void kernel_launch(void* const* d_in, const int* in_sizes, int n_in,
                              void* d_out, int out_size, void* d_ws, size_t ws_size,
                              hipStream_t stream) {
    const float* mu  = (const float*)d_in[0];
    const float* ls  = (const float*)d_in[1];
    const float* eps = (const float*)d_in[2];
    const float* W   = (const float*)d_in[3];
    char* ws = (char*)d_ws;

    uint8_t* Wp8 = (uint8_t*)(ws);
    uint8_t* Ap8 = (uint8_t*)(ws + 12845056L);
    float* pm  = (float*)(ws + 13500416L);
    float* ps  = (float*)(ws + 15507456L);
    float* bs  = (float*)(ws + 17514496L);
    float* Ms  = (float*)(ws + 17524736L);
    float* Ss  = (float*)(ws + 17534976L);
    float* kl  = (float*)d_out + 125000000L;

    k1_prep<<<2048, 256, 0, stream>>>(mu, ls, eps, W, Ap8, Wp8, bs);
    k2_pass1<<<NTM * NTN, 512, 0, stream>>>(Ap8, Wp8, pm, ps);
    k3_stats<<<41, 256, 0, stream>>>(pm, ps, bs, Ms, Ss, kl);
    k2_pass2<<<NTM * NTN, 512, 0, stream>>>(Ap8, Wp8, Ms, Ss, (float*)d_out);
}